// Round 6
// baseline (119.879 us; speedup 1.0000x reference)
//
#include <hip/hip_runtime.h>

// Problem constants (from reference)
#define T_TOKENS 4096      // B*C = 4*1024
#define D_DIM    2048
#define NEXP     8
#define CAP      1280      // floor(2 * 1.25 * 4096 / 8), already even
#define NSLOTS   (NEXP * CAP)   // 10240

#define GATE_BLOCKS (T_TOKENS / 4)               // 1024
#define FILL_FLOATS (2ull * T_TOKENS * NSLOTS)   // exp_weights + exp_mask = 83,886,080
#define FILL_VECS   (FILL_FLOATS / 4)            // 20,971,520 f32x4
#define FILL_BLOCKS 5120
#define FILL_THREADS (FILL_BLOCKS * 256)         // 1,310,720 -> 16 stores/thread

// native 16-byte vector type
typedef float f32x4 __attribute__((ext_vector_type(4)));

// ---------------------------------------------------------------------------
// Kernel 1 (fused): blocks [0, GATE_BLOCKS) run gating (4 tokens each, one
// wave per token); remaining FILL_BLOCKS zero-fill exp_weights + exp_mask
// with a rocclr-style grid-stride pattern and PLAIN stores (A/B vs round 5's
// nontemporal block-chunk stores).
// ---------------------------------------------------------------------------
__global__ void gate_fill_kernel(const float* __restrict__ x,
                                 const float* __restrict__ noise,
                                 const float* __restrict__ w_g,
                                 const float* __restrict__ w_noise,
                                 int*   __restrict__ top_idx,    // [2*T] slot-major
                                 float* __restrict__ top_prob,   // [2*T] slot-major
                                 float* __restrict__ wm_base)    // exp_weights (mask follows)
{
    if (blockIdx.x >= GATE_BLOCKS) {
        // ---- zero-fill portion: grid-stride, plain stores ----
        const size_t tid = (size_t)(blockIdx.x - GATE_BLOCKS) * 256 + threadIdx.x;
        f32x4* dst = reinterpret_cast<f32x4*>(wm_base);
        const f32x4 z = {0.f, 0.f, 0.f, 0.f};
#pragma unroll
        for (int j = 0; j < (int)(FILL_VECS / FILL_THREADS); ++j)
            dst[(size_t)j * FILL_THREADS + tid] = z;
        return;
    }

    // ---- gating portion ----
    const int wave = threadIdx.x >> 6;
    const int lane = threadIdx.x & 63;
    const int t = blockIdx.x * 4 + wave;

    const f32x4* xv = reinterpret_cast<const f32x4*>(x + (size_t)t * D_DIM);

    float acc[16];
#pragma unroll
    for (int j = 0; j < 16; ++j) acc[j] = 0.f;

#pragma unroll
    for (int it = 0; it < 8; ++it) {
        const int c = it * 64 + lane;   // float4 column index
        const f32x4 xval = xv[c];
#pragma unroll
        for (int e = 0; e < NEXP; ++e) {
            const f32x4 g = reinterpret_cast<const f32x4*>(w_g + (size_t)e * D_DIM)[c];
            acc[e] += xval.x * g.x + xval.y * g.y + xval.z * g.z + xval.w * g.w;
            const f32x4 n = reinterpret_cast<const f32x4*>(w_noise + (size_t)e * D_DIM)[c];
            acc[8 + e] += xval.x * n.x + xval.y * n.y + xval.z * n.z + xval.w * n.w;
        }
    }

#pragma unroll
    for (int j = 0; j < 16; ++j) {
        float v = acc[j];
#pragma unroll
        for (int off = 32; off > 0; off >>= 1) v += __shfl_down(v, off, 64);
        acc[j] = v;   // valid on lane 0
    }

    if (lane == 0) {
        float logit[NEXP];
#pragma unroll
        for (int e = 0; e < NEXP; ++e) {
            const float z = acc[8 + e];
            const float sp = fmaxf(z, 0.f) + log1pf(expf(-fabsf(z)));  // stable softplus
            logit[e] = acc[e] + sp * noise[(size_t)t * NEXP + e];
        }
        int i0 = 0; float v0 = logit[0];
#pragma unroll
        for (int e = 1; e < NEXP; ++e) {
            if (logit[e] > v0) { v0 = logit[e]; i0 = e; }
        }
        int i1 = -1; float v1 = -3.402823466e38f;
#pragma unroll
        for (int e = 0; e < NEXP; ++e) {
            if (e != i0 && logit[e] > v1) { v1 = logit[e]; i1 = e; }
        }
        const float e1  = expf(v1 - v0);
        const float inv = 1.f / (1.f + e1);
        top_idx[t]            = i0;
        top_idx[T_TOKENS + t] = i1;
        top_prob[t]            = inv;
        top_prob[T_TOKENS + t] = e1 * inv;
    }
}

// ---------------------------------------------------------------------------
// Kernel 2: per-expert capacity scan + sparse scatter. One block per expert
// (8 blocks, 512 threads = 8 waves). Two-phase: per-wave counts -> exclusive
// prefix -> rank pass that scatters the (weight, mask) scalars onto the
// zeroed buffers and builds slot_token (its own range inited, no memset).
// ---------------------------------------------------------------------------
__global__ void scan_scatter_kernel(const int*   __restrict__ top_idx,
                                    const float* __restrict__ top_prob,
                                    int*   __restrict__ slot_token,     // [NSLOTS]
                                    float* __restrict__ exp_weights,    // [T,8,CAP]
                                    float* __restrict__ exp_mask)       // [T,8,CAP]
{
    __shared__ int sidx[2 * T_TOKENS];   // 32 KB
    __shared__ int scnt[8];

    const int e    = blockIdx.x;         // expert
    const int w    = threadIdx.x >> 6;   // wave id (0..7)
    const int lane = threadIdx.x & 63;

    for (int i = threadIdx.x; i < 2 * T_TOKENS; i += 512)
        sidx[i] = top_idx[i];
    for (int r = threadIdx.x; r < CAP; r += 512)
        slot_token[e * CAP + r] = -1;
    __syncthreads();

    // phase A: wave w counts matches in its contiguous 16-chunk range
    int cnt = 0;
#pragma unroll
    for (int c = 0; c < 16; ++c) {
        const int i = (w * 16 + c) * 64 + lane;
        cnt += __popcll(__ballot(sidx[i] == e));
    }
    if (lane == 0) scnt[w] = cnt;
    __syncthreads();

    int base = 0;
#pragma unroll
    for (int j = 0; j < 8; ++j) if (j < w) base += scnt[j];

    // phase B: assign ranks, scatter scalars, build slot map
#pragma unroll
    for (int c = 0; c < 16; ++c) {
        const int i = (w * 16 + c) * 64 + lane;
        const bool match = (sidx[i] == e);
        const unsigned long long m = __ballot(match);
        if (match) {
            const int r = base + __popcll(m & ((1ull << lane) - 1ull));
            if (r < CAP) {
                slot_token[e * CAP + r] = i;
                const int t = i & (T_TOKENS - 1);
                const float wgt = top_prob[i];
                const size_t off = (size_t)t * NSLOTS + e * CAP + r;
                exp_weights[off] = wgt;
                exp_mask[off]    = (wgt != 0.f) ? 1.f : 0.f;
            }
        }
        base += __popcll(m);
    }
}

// ---------------------------------------------------------------------------
// Kernel 3: expert_batches — every byte written exactly once, plain stores.
// One block per (expert, cap) slot: copy x[t] if filled, zeros otherwise.
// ---------------------------------------------------------------------------
__global__ void batches_kernel(const float* __restrict__ x,
                               const int*   __restrict__ slot_token,
                               float* __restrict__ expert_batches) // [8,CAP,D]
{
    const int slot = blockIdx.x;          // e*CAP + r
    const int i = slot_token[slot];
    f32x4* dst = reinterpret_cast<f32x4*>(expert_batches + (size_t)slot * D_DIM);

    if (i >= 0) {
        const int t = i & (T_TOKENS - 1);
        const f32x4* src = reinterpret_cast<const f32x4*>(x + (size_t)t * D_DIM);
#pragma unroll
        for (int c = threadIdx.x; c < D_DIM / 4; c += 256)
            dst[c] = src[c];
    } else {
        const f32x4 z = {0.f, 0.f, 0.f, 0.f};
#pragma unroll
        for (int c = threadIdx.x; c < D_DIM / 4; c += 256)
            dst[c] = z;
    }
}

// ---------------------------------------------------------------------------
extern "C" void kernel_launch(void* const* d_in, const int* in_sizes, int n_in,
                              void* d_out, int out_size, void* d_ws, size_t ws_size,
                              hipStream_t stream)
{
    const float* x       = (const float*)d_in[0];
    const float* noise   = (const float*)d_in[1];
    const float* w_g     = (const float*)d_in[2];
    const float* w_noise = (const float*)d_in[3];

    float* out = (float*)d_out;
    const size_t n_ew = (size_t)T_TOKENS * NEXP * CAP;   // 41,943,040
    float* exp_weights    = out;
    float* exp_mask       = out + n_ew;
    float* expert_batches = out + 2 * n_ew;

    int*   top_idx    = (int*)d_ws;                                      // 8192 ints
    float* top_prob   = (float*)((char*)d_ws + 2 * T_TOKENS * 4);        // 8192 floats
    int*   slot_token = (int*)((char*)d_ws + 4 * T_TOKENS * 4);          // 10240 ints

    gate_fill_kernel<<<GATE_BLOCKS + FILL_BLOCKS, 256, 0, stream>>>(
        x, noise, w_g, w_noise, top_idx, top_prob, exp_weights);
    scan_scatter_kernel<<<NEXP, 512, 0, stream>>>(top_idx, top_prob, slot_token,
                                                  exp_weights, exp_mask);
    batches_kernel<<<NSLOTS, 256, 0, stream>>>(x, slot_token, expert_batches);
}